// Round 1
// baseline (1685.790 us; speedup 1.0000x reference)
//
#include <hip/hip_runtime.h>

#define HDIM 108
#define HPAD 112
constexpr int G_GRAPHS = 128;

// ---------------- CSR build ----------------

__global__ __launch_bounds__(256) void k_deg(const int* __restrict__ dst, int* __restrict__ deg, int E) {
  int e = blockIdx.x * 256 + threadIdx.x;
  if (e < E) atomicAdd(&deg[dst[e]], 1);
}

__global__ __launch_bounds__(256) void k_blocksum(const int* __restrict__ deg, int* __restrict__ bsum, int N) {
  __shared__ int s[256];
  int t = threadIdx.x;
  int i = blockIdx.x * 256 + t;
  s[t] = (i < N) ? deg[i] : 0;
  __syncthreads();
  for (int off = 128; off > 0; off >>= 1) {
    if (t < off) s[t] += s[t + off];
    __syncthreads();
  }
  if (t == 0) bsum[blockIdx.x] = s[0];
}

__global__ __launch_bounds__(512) void k_scan_bsum(const int* __restrict__ bsum, int* __restrict__ boff, int nb) {
  __shared__ int s[512];
  int t = threadIdx.x;
  int own = (t < nb) ? bsum[t] : 0;
  s[t] = own;
  __syncthreads();
  for (int off = 1; off < 512; off <<= 1) {
    int x = (t >= off) ? s[t - off] : 0;
    __syncthreads();
    s[t] += x;
    __syncthreads();
  }
  if (t < nb) boff[t] = s[t] - own;  // exclusive
}

__global__ __launch_bounds__(256) void k_scan_final(const int* __restrict__ deg, const int* __restrict__ boff,
                                                    int* __restrict__ rowStart, int* __restrict__ cursor, int N) {
  __shared__ int s[256];
  int t = threadIdx.x;
  int i = blockIdx.x * 256 + t;
  int own = (i < N) ? deg[i] : 0;
  s[t] = own;
  __syncthreads();
  for (int off = 1; off < 256; off <<= 1) {
    int x = (t >= off) ? s[t - off] : 0;
    __syncthreads();
    s[t] += x;
    __syncthreads();
  }
  if (i < N) {
    int rs = boff[blockIdx.x] + s[t] - own;
    rowStart[i] = rs;
    cursor[i] = rs;
  }
}

__global__ __launch_bounds__(256) void k_fill(const int* __restrict__ src, const int* __restrict__ dst,
                                              int* __restrict__ cursor, int* __restrict__ csr, int E) {
  int e = blockIdx.x * 256 + threadIdx.x;
  if (e < E) {
    int pos = atomicAdd(&cursor[dst[e]], 1);
    csr[pos] = src[e];  // store source node id directly
  }
}

// ---------------- GEMM: out[N,108] = A[N,K] @ W[K,108] (+bias, act) ----------------
// Block: 256 threads, 128-node tile. Thread (ni=tid>>4, oi=tid&15) computes
// 8 nodes x 7 cols (cols = oi + 16*j). K staged in LDS chunks of KC.
// MODE 0: plain (embedding). MODE 1: ReLU (pool). MODE 2: bias->row L2 norm->ReLU->residual into out (==h, in place).

template <int K, int KC, int MODE>
__global__ __launch_bounds__(256) void k_mm(const float* A, const float* __restrict__ A2,
                                            const float* __restrict__ Wg, const float* __restrict__ bias,
                                            float* out, int N) {
  constexpr int KCP = KC + 1;  // odd stride -> conflict-free LDS
  __shared__ float As[128 * KCP];
  __shared__ float Ws[KC * HPAD];
  const int tid = threadIdx.x;
  const int oi = tid & 15;
  const int ni = tid >> 4;
  const int n0 = blockIdx.x * 128;

  float acc[8][7];
#pragma unroll
  for (int m = 0; m < 8; m++)
#pragma unroll
    for (int j = 0; j < 7; j++) acc[m][j] = 0.f;

  for (int k0 = 0; k0 < K; k0 += KC) {
    // stage A tile (zero-pad beyond N)
#pragma unroll 1
    for (int idx = tid; idx < 128 * KC; idx += 256) {
      int n = idx / KC, k = idx - n * KC;
      int gn = n0 + n;
      float v = 0.f;
      if (gn < N) {
        int kt = k0 + k;
        if (K == 216)
          v = (kt < HDIM) ? A[gn * HDIM + kt] : A2[gn * HDIM + (kt - HDIM)];
        else
          v = A[gn * K + kt];
      }
      As[n * KCP + k] = v;
    }
    // stage W chunk (zero-pad cols 108..111)
#pragma unroll 1
    for (int idx = tid; idx < KC * HPAD; idx += 256) {
      int k = idx / HPAD, o = idx - k * HPAD;
      Ws[idx] = (o < HDIM) ? Wg[(k0 + k) * HDIM + o] : 0.f;
    }
    __syncthreads();

#pragma unroll 2
    for (int k = 0; k < KC; k++) {
      float a[8], w[7];
#pragma unroll
      for (int m = 0; m < 8; m++) a[m] = As[(ni * 8 + m) * KCP + k];
#pragma unroll
      for (int j = 0; j < 7; j++) w[j] = Ws[k * HPAD + j * 16 + oi];
#pragma unroll
      for (int m = 0; m < 8; m++)
#pragma unroll
        for (int j = 0; j < 7; j++) acc[m][j] = fmaf(a[m], w[j], acc[m][j]);
    }
    __syncthreads();
  }

  if (MODE == 2) {
#pragma unroll 1
    for (int m = 0; m < 8; m++) {
      int gn = n0 + ni * 8 + m;
      float bb[7];
      float ssq = 0.f;
#pragma unroll
      for (int j = 0; j < 7; j++) {
        int col = j * 16 + oi;
        float v = acc[m][j];
        if (col < HDIM) v += bias[col]; else v = 0.f;
        bb[j] = v;
        ssq += v * v;
      }
      // reduce across the 16 oi-lanes (lane low 4 bits == oi)
#pragma unroll
      for (int s = 1; s < 16; s <<= 1) ssq += __shfl_xor(ssq, s, 64);
      float scale = 1.f / fmaxf(sqrtf(ssq), 1e-12f);
      if (gn < N) {
#pragma unroll
        for (int j = 0; j < 7; j++) {
          int col = j * 16 + oi;
          if (col < HDIM) {
            float hv = out[gn * HDIM + col];  // h_in (unchanged this layer until here)
            out[gn * HDIM + col] = hv + fmaxf(bb[j] * scale, 0.f);
          }
        }
      }
    }
  } else {
#pragma unroll 1
    for (int m = 0; m < 8; m++) {
      int gn = n0 + ni * 8 + m;
      if (gn < N) {
#pragma unroll
        for (int j = 0; j < 7; j++) {
          int col = j * 16 + oi;
          if (col < HDIM) {
            float v = acc[m][j] + bias[col];
            if (MODE == 1) v = fmaxf(v, 0.f);
            out[gn * HDIM + col] = v;
          }
        }
      }
    }
  }
}

// ---------------- edge aggregation: c[v] = mean_{e: dst==v} z[src[e]] ----------------
__global__ __launch_bounds__(128) void k_agg(const float* __restrict__ z, const int* __restrict__ csr,
                                             const int* __restrict__ rowStart, const int* __restrict__ deg,
                                             float* __restrict__ c, int N) {
  int v = blockIdx.x;
  int t = threadIdx.x;
  if (t >= HDIM) return;
  int rs = rowStart[v];   // wave-uniform -> scalar loads
  int d = deg[v];
  const int* nb = csr + rs;
  float acc = 0.f;
  int j = 0;
  for (; j + 4 <= d; j += 4) {
    int s0 = nb[j], s1 = nb[j + 1], s2 = nb[j + 2], s3 = nb[j + 3];
    acc += z[s0 * HDIM + t];
    acc += z[s1 * HDIM + t];
    acc += z[s2 * HDIM + t];
    acc += z[s3 * HDIM + t];
  }
  for (; j < d; j++) acc += z[nb[j] * HDIM + t];
  float dn = (d > 0) ? (float)d : 1.f;
  c[v * HDIM + t] = acc / dn;
}

// ---------------- readout ----------------
__global__ __launch_bounds__(256) void k_cnt(const int* __restrict__ gid, int* __restrict__ cnt, int N) {
  int i = blockIdx.x * 256 + threadIdx.x;
  if (i < N) atomicAdd(&cnt[gid[i]], 1);
}

__global__ __launch_bounds__(128) void k_readout(const float* __restrict__ h, const int* __restrict__ gid,
                                                 float* __restrict__ hg, int N) {
  const int RCHUNK = 256;
  int t = threadIdx.x;
  if (t >= HDIM) return;
  int start = blockIdx.x * RCHUNK;
  int end = min(start + RCHUNK, N);
  float acc = 0.f;
  int cur = gid[start];  // sorted graph_ids -> run-length pre-aggregation
  for (int i = start; i < end; i++) {
    int g = gid[i];
    if (g != cur) {
      atomicAdd(&hg[cur * HDIM + t], acc);
      acc = 0.f;
      cur = g;
    }
    acc += h[i * HDIM + t];
  }
  atomicAdd(&hg[cur * HDIM + t], acc);
}

__global__ __launch_bounds__(256) void k_div(const float* __restrict__ hg, const int* __restrict__ cnt,
                                             float* __restrict__ out, int total) {
  int i = blockIdx.x * 256 + threadIdx.x;
  if (i < total) {
    int g = i / HDIM;
    int c = cnt[g];
    out[i] = hg[i] / (float)(c > 0 ? c : 1);
  }
}

// ---------------- launch ----------------
extern "C" void kernel_launch(void* const* d_in, const int* in_sizes, int n_in,
                              void* d_out, int out_size, void* d_ws, size_t ws_size,
                              hipStream_t stream) {
  (void)n_in; (void)ws_size; (void)out_size;
  const float* nodes_feat = (const float*)d_in[0];
  const float* W_emb = (const float*)d_in[4];
  const float* b_emb = (const float*)d_in[5];
  const float* pool_W = (const float*)d_in[6];
  const float* pool_b = (const float*)d_in[7];
  const float* app_W = (const float*)d_in[8];
  const float* app_b = (const float*)d_in[9];
  const int* src = (const int*)d_in[10];
  const int* dst = (const int*)d_in[11];
  const int* gid = (const int*)d_in[12];
  const int N = in_sizes[2];
  const int E = in_sizes[10];
  float* out = (float*)d_out;

  char* ws = (char*)d_ws;
  size_t off = 0;
  auto alloc = [&](size_t bytes) -> size_t {
    size_t o = off;
    off += (bytes + 1023) & ~size_t(1023);
    return o;
  };
  size_t o_deg = alloc((size_t)N * 4);
  size_t o_cnt = alloc((size_t)G_GRAPHS * 4);
  size_t o_hg  = alloc((size_t)G_GRAPHS * HDIM * 4);
  size_t zero_bytes = off;  // [deg, cnt, hg] zeroed in one memset
  size_t o_rs   = alloc((size_t)N * 4);
  size_t o_cur  = alloc((size_t)N * 4);
  size_t o_csr  = alloc((size_t)E * 4);
  size_t o_bsum = alloc(2048);
  size_t o_boff = alloc(2048);
  size_t o_h = alloc((size_t)N * HDIM * 4);
  size_t o_z = alloc((size_t)N * HDIM * 4);
  size_t o_c = alloc((size_t)N * HDIM * 4);

  int* deg      = (int*)(ws + o_deg);
  int* cnt      = (int*)(ws + o_cnt);
  float* hg     = (float*)(ws + o_hg);
  int* rowStart = (int*)(ws + o_rs);
  int* cursor   = (int*)(ws + o_cur);
  int* csr      = (int*)(ws + o_csr);
  int* bsum     = (int*)(ws + o_bsum);
  int* boff     = (int*)(ws + o_boff);
  float* h = (float*)(ws + o_h);
  float* z = (float*)(ws + o_z);
  float* c = (float*)(ws + o_c);

  hipMemsetAsync(d_ws, 0, zero_bytes, stream);

  const int nbE = (E + 255) / 256;
  const int nbN = (N + 255) / 256;  // 391 <= 512 (single-block top scan)
  k_deg<<<nbE, 256, 0, stream>>>(dst, deg, E);
  k_blocksum<<<nbN, 256, 0, stream>>>(deg, bsum, N);
  k_scan_bsum<<<1, 512, 0, stream>>>(bsum, boff, nbN);
  k_scan_final<<<nbN, 256, 0, stream>>>(deg, boff, rowStart, cursor, N);
  k_fill<<<nbE, 256, 0, stream>>>(src, dst, cursor, csr, E);

  const int nbMM = (N + 127) / 128;
  k_mm<64, 32, 0><<<nbMM, 256, 0, stream>>>(nodes_feat, nullptr, W_emb, b_emb, h, N);

  for (int i = 0; i < 2; i++) {
    k_mm<108, 54, 1><<<nbMM, 256, 0, stream>>>(h, nullptr, pool_W + i * HDIM * HDIM,
                                               pool_b + i * HDIM, z, N);
    k_agg<<<N, 128, 0, stream>>>(z, csr, rowStart, deg, c, N);
    k_mm<216, 54, 2><<<nbMM, 256, 0, stream>>>(h, c, app_W + i * 2 * HDIM * HDIM,
                                               app_b + i * HDIM, h, N);
  }

  k_cnt<<<nbN, 256, 0, stream>>>(gid, cnt, N);
  k_readout<<<nbN, 128, 0, stream>>>(h, gid, hg, N);
  k_div<<<(G_GRAPHS * HDIM + 255) / 256, 256, 0, stream>>>(hg, cnt, out, G_GRAPHS * HDIM);
}

// Round 2
// 1369.635 us; speedup vs baseline: 1.2308x; 1.2308x over previous
//
#include <hip/hip_runtime.h>

#define HDIM 108
#define HPAD 112
constexpr int G_GRAPHS = 128;

// ---------------- CSR build ----------------

__global__ __launch_bounds__(256) void k_deg(const int* __restrict__ dst, int* __restrict__ deg, int E) {
  int e = blockIdx.x * 256 + threadIdx.x;
  if (e < E) atomicAdd(&deg[dst[e]], 1);
}

__global__ __launch_bounds__(256) void k_blocksum(const int* __restrict__ deg, int* __restrict__ bsum, int N) {
  __shared__ int s[256];
  int t = threadIdx.x;
  int i = blockIdx.x * 256 + t;
  s[t] = (i < N) ? deg[i] : 0;
  __syncthreads();
  for (int off = 128; off > 0; off >>= 1) {
    if (t < off) s[t] += s[t + off];
    __syncthreads();
  }
  if (t == 0) bsum[blockIdx.x] = s[0];
}

__global__ __launch_bounds__(512) void k_scan_bsum(const int* __restrict__ bsum, int* __restrict__ boff, int nb) {
  __shared__ int s[512];
  int t = threadIdx.x;
  int own = (t < nb) ? bsum[t] : 0;
  s[t] = own;
  __syncthreads();
  for (int off = 1; off < 512; off <<= 1) {
    int x = (t >= off) ? s[t - off] : 0;
    __syncthreads();
    s[t] += x;
    __syncthreads();
  }
  if (t < nb) boff[t] = s[t] - own;  // exclusive
}

__global__ __launch_bounds__(256) void k_scan_final(const int* __restrict__ deg, const int* __restrict__ boff,
                                                    int* __restrict__ rowStart, int* __restrict__ cursor, int N) {
  __shared__ int s[256];
  int t = threadIdx.x;
  int i = blockIdx.x * 256 + t;
  int own = (i < N) ? deg[i] : 0;
  s[t] = own;
  __syncthreads();
  for (int off = 1; off < 256; off <<= 1) {
    int x = (t >= off) ? s[t - off] : 0;
    __syncthreads();
    s[t] += x;
    __syncthreads();
  }
  if (i < N) {
    int rs = boff[blockIdx.x] + s[t] - own;
    rowStart[i] = rs;
    cursor[i] = rs;
  }
}

__global__ __launch_bounds__(256) void k_fill(const int* __restrict__ src, const int* __restrict__ dst,
                                              int* __restrict__ cursor, int* __restrict__ csr, int E) {
  int e = blockIdx.x * 256 + threadIdx.x;
  if (e < E) {
    int pos = atomicAdd(&cursor[dst[e]], 1);
    csr[pos] = src[e];  // store source node id directly
  }
}

// ---------------- GEMM: out[N,108] = A[N,K] @ W[K,108] (+bias, act) ----------------
// Block: 256 threads, 128-node tile. Thread (ni=tid>>4, oi=tid&15) computes
// 8 nodes x 7 cols (cols = oi + 16*j). K staged in LDS chunks of KC.
// MODE 0: plain (embedding). MODE 1: ReLU (pool). MODE 2: bias->row L2 norm->ReLU->residual into out (==h, in place).

template <int K, int KC, int MODE>
__global__ __launch_bounds__(256) void k_mm(const float* A, const float* __restrict__ A2,
                                            const float* __restrict__ Wg, const float* __restrict__ bias,
                                            float* out, int N) {
  constexpr int KCP = KC + 1;  // odd stride -> conflict-free LDS
  __shared__ float As[128 * KCP];
  __shared__ float Ws[KC * HPAD];
  const int tid = threadIdx.x;
  const int oi = tid & 15;
  const int ni = tid >> 4;
  const int n0 = blockIdx.x * 128;

  float acc[8][7];
#pragma unroll
  for (int m = 0; m < 8; m++)
#pragma unroll
    for (int j = 0; j < 7; j++) acc[m][j] = 0.f;

  for (int k0 = 0; k0 < K; k0 += KC) {
    // stage A tile (zero-pad beyond N)
#pragma unroll 1
    for (int idx = tid; idx < 128 * KC; idx += 256) {
      int n = idx / KC, k = idx - n * KC;
      int gn = n0 + n;
      float v = 0.f;
      if (gn < N) {
        int kt = k0 + k;
        if (K == 216)
          v = (kt < HDIM) ? A[gn * HDIM + kt] : A2[gn * HDIM + (kt - HDIM)];
        else
          v = A[gn * K + kt];
      }
      As[n * KCP + k] = v;
    }
    // stage W chunk (zero-pad cols 108..111)
#pragma unroll 1
    for (int idx = tid; idx < KC * HPAD; idx += 256) {
      int k = idx / HPAD, o = idx - k * HPAD;
      Ws[idx] = (o < HDIM) ? Wg[(k0 + k) * HDIM + o] : 0.f;
    }
    __syncthreads();

#pragma unroll 2
    for (int k = 0; k < KC; k++) {
      float a[8], w[7];
#pragma unroll
      for (int m = 0; m < 8; m++) a[m] = As[(ni * 8 + m) * KCP + k];
#pragma unroll
      for (int j = 0; j < 7; j++) w[j] = Ws[k * HPAD + j * 16 + oi];
#pragma unroll
      for (int m = 0; m < 8; m++)
#pragma unroll
        for (int j = 0; j < 7; j++) acc[m][j] = fmaf(a[m], w[j], acc[m][j]);
    }
    __syncthreads();
  }

  if (MODE == 2) {
#pragma unroll 1
    for (int m = 0; m < 8; m++) {
      int gn = n0 + ni * 8 + m;
      float bb[7];
      float ssq = 0.f;
#pragma unroll
      for (int j = 0; j < 7; j++) {
        int col = j * 16 + oi;
        float v = acc[m][j];
        if (col < HDIM) v += bias[col]; else v = 0.f;
        bb[j] = v;
        ssq += v * v;
      }
      // reduce across the 16 oi-lanes (lane low 4 bits == oi)
#pragma unroll
      for (int s = 1; s < 16; s <<= 1) ssq += __shfl_xor(ssq, s, 64);
      float scale = 1.f / fmaxf(sqrtf(ssq), 1e-12f);
      if (gn < N) {
#pragma unroll
        for (int j = 0; j < 7; j++) {
          int col = j * 16 + oi;
          if (col < HDIM) {
            float hv = out[gn * HDIM + col];  // h_in (unchanged this layer until here)
            out[gn * HDIM + col] = hv + fmaxf(bb[j] * scale, 0.f);
          }
        }
      }
    }
  } else {
#pragma unroll 1
    for (int m = 0; m < 8; m++) {
      int gn = n0 + ni * 8 + m;
      if (gn < N) {
#pragma unroll
        for (int j = 0; j < 7; j++) {
          int col = j * 16 + oi;
          if (col < HDIM) {
            float v = acc[m][j] + bias[col];
            if (MODE == 1) v = fmaxf(v, 0.f);
            out[gn * HDIM + col] = v;
          }
        }
      }
    }
  }
}

// ---------------- edge aggregation: c[v] = mean_{e: dst==v} z[src[e]] ----------------
// float4 version: 108 floats = 27 float4 exactly. 32-lane group per node (27 active),
// 8 nodes per 256-thread block. Neighbor index loads are group-uniform (broadcast).
__global__ __launch_bounds__(256) void k_agg(const float* __restrict__ z, const int* __restrict__ csr,
                                             const int* __restrict__ rowStart, const int* __restrict__ deg,
                                             float* __restrict__ c, int N) {
  const int lane = threadIdx.x & 31;
  const int grp = threadIdx.x >> 5;
  const int v = blockIdx.x * 8 + grp;
  if (v >= N || lane >= 27) return;
  const float4* __restrict__ z4 = (const float4*)z;
  int rs = rowStart[v];
  int d = deg[v];
  const int* nb = csr + rs;
  float4 acc = {0.f, 0.f, 0.f, 0.f};
  int j = 0;
  for (; j + 4 <= d; j += 4) {
    int s0 = nb[j], s1 = nb[j + 1], s2 = nb[j + 2], s3 = nb[j + 3];
    float4 v0 = z4[(size_t)s0 * 27 + lane];
    float4 v1 = z4[(size_t)s1 * 27 + lane];
    float4 v2 = z4[(size_t)s2 * 27 + lane];
    float4 v3 = z4[(size_t)s3 * 27 + lane];
    acc.x += v0.x + v1.x + v2.x + v3.x;
    acc.y += v0.y + v1.y + v2.y + v3.y;
    acc.z += v0.z + v1.z + v2.z + v3.z;
    acc.w += v0.w + v1.w + v2.w + v3.w;
  }
  for (; j < d; j++) {
    float4 v0 = z4[(size_t)nb[j] * 27 + lane];
    acc.x += v0.x; acc.y += v0.y; acc.z += v0.z; acc.w += v0.w;
  }
  float dn = (d > 0) ? (float)d : 1.f;
  float inv = 1.f / dn;
  float4* c4 = (float4*)c;
  float4 r;
  r.x = acc.x * inv; r.y = acc.y * inv; r.z = acc.z * inv; r.w = acc.w * inv;
  c4[(size_t)v * 27 + lane] = r;
}

// ---------------- readout ----------------
// cnt via binary search on sorted graph_ids (no atomics).
__global__ __launch_bounds__(128) void k_cnt_bs(const int* __restrict__ gid, int* __restrict__ cnt, int N) {
  int g = threadIdx.x;
  if (g >= G_GRAPHS) return;
  int lo = 0, hi = N;
  while (lo < hi) { int m = (lo + hi) >> 1; if (gid[m] < g) lo = m + 1; else hi = m; }
  int lb = lo;
  lo = 0; hi = N;
  while (lo < hi) { int m = (lo + hi) >> 1; if (gid[m] <= g) lo = m + 1; else hi = m; }
  cnt[g] = lo - lb;
}

// float4 run-length readout: 32-lane group (27 active) handles 64 rows.
__global__ __launch_bounds__(256) void k_readout(const float* __restrict__ h, const int* __restrict__ gid,
                                                 float* __restrict__ hg, int N) {
  const int CH = 64;
  const int lane = threadIdx.x & 31;
  const int grp = threadIdx.x >> 5;
  int start = (blockIdx.x * 8 + grp) * CH;
  if (start >= N || lane >= 27) return;
  int end = min(start + CH, N);
  const float4* __restrict__ h4 = (const float4*)h;
  float4 acc = {0.f, 0.f, 0.f, 0.f};
  int cur = gid[start];  // sorted graph_ids -> run-length pre-aggregation
  for (int i = start; i < end; i++) {
    int g = gid[i];
    if (g != cur) {
      float* base = &hg[(size_t)cur * HDIM + lane * 4];
      atomicAdd(base + 0, acc.x); atomicAdd(base + 1, acc.y);
      atomicAdd(base + 2, acc.z); atomicAdd(base + 3, acc.w);
      acc.x = acc.y = acc.z = acc.w = 0.f;
      cur = g;
    }
    float4 v = h4[(size_t)i * 27 + lane];
    acc.x += v.x; acc.y += v.y; acc.z += v.z; acc.w += v.w;
  }
  float* base = &hg[(size_t)cur * HDIM + lane * 4];
  atomicAdd(base + 0, acc.x); atomicAdd(base + 1, acc.y);
  atomicAdd(base + 2, acc.z); atomicAdd(base + 3, acc.w);
}

__global__ __launch_bounds__(256) void k_div(const float* __restrict__ hg, const int* __restrict__ cnt,
                                             float* __restrict__ out, int total) {
  int i = blockIdx.x * 256 + threadIdx.x;
  if (i < total) {
    int g = i / HDIM;
    int c = cnt[g];
    out[i] = hg[i] / (float)(c > 0 ? c : 1);
  }
}

// ---------------- launch ----------------
extern "C" void kernel_launch(void* const* d_in, const int* in_sizes, int n_in,
                              void* d_out, int out_size, void* d_ws, size_t ws_size,
                              hipStream_t stream) {
  (void)n_in; (void)ws_size; (void)out_size;
  const float* nodes_feat = (const float*)d_in[0];
  const float* W_emb = (const float*)d_in[4];
  const float* b_emb = (const float*)d_in[5];
  const float* pool_W = (const float*)d_in[6];
  const float* pool_b = (const float*)d_in[7];
  const float* app_W = (const float*)d_in[8];
  const float* app_b = (const float*)d_in[9];
  const int* src = (const int*)d_in[10];
  const int* dst = (const int*)d_in[11];
  const int* gid = (const int*)d_in[12];
  const int N = in_sizes[2];
  const int E = in_sizes[10];
  float* out = (float*)d_out;

  char* ws = (char*)d_ws;
  size_t off = 0;
  auto alloc = [&](size_t bytes) -> size_t {
    size_t o = off;
    off += (bytes + 1023) & ~size_t(1023);
    return o;
  };
  size_t o_deg = alloc((size_t)N * 4);
  size_t o_cnt = alloc((size_t)G_GRAPHS * 4);
  size_t o_hg  = alloc((size_t)G_GRAPHS * HDIM * 4);
  size_t zero_bytes = off;  // [deg, cnt, hg] zeroed in one memset
  size_t o_rs   = alloc((size_t)N * 4);
  size_t o_cur  = alloc((size_t)N * 4);
  size_t o_csr  = alloc((size_t)E * 4);
  size_t o_bsum = alloc(2048);
  size_t o_boff = alloc(2048);
  size_t o_h = alloc((size_t)N * HDIM * 4);
  size_t o_z = alloc((size_t)N * HDIM * 4);
  size_t o_c = alloc((size_t)N * HDIM * 4);

  int* deg      = (int*)(ws + o_deg);
  int* cnt      = (int*)(ws + o_cnt);
  float* hg     = (float*)(ws + o_hg);
  int* rowStart = (int*)(ws + o_rs);
  int* cursor   = (int*)(ws + o_cur);
  int* csr      = (int*)(ws + o_csr);
  int* bsum     = (int*)(ws + o_bsum);
  int* boff     = (int*)(ws + o_boff);
  float* h = (float*)(ws + o_h);
  float* z = (float*)(ws + o_z);
  float* c = (float*)(ws + o_c);

  hipMemsetAsync(d_ws, 0, zero_bytes, stream);

  const int nbE = (E + 255) / 256;
  const int nbN = (N + 255) / 256;  // 391 <= 512 (single-block top scan)
  k_deg<<<nbE, 256, 0, stream>>>(dst, deg, E);
  k_blocksum<<<nbN, 256, 0, stream>>>(deg, bsum, N);
  k_scan_bsum<<<1, 512, 0, stream>>>(bsum, boff, nbN);
  k_scan_final<<<nbN, 256, 0, stream>>>(deg, boff, rowStart, cursor, N);
  k_fill<<<nbE, 256, 0, stream>>>(src, dst, cursor, csr, E);

  const int nbMM = (N + 127) / 128;
  k_mm<64, 32, 0><<<nbMM, 256, 0, stream>>>(nodes_feat, nullptr, W_emb, b_emb, h, N);

  for (int i = 0; i < 2; i++) {
    k_mm<108, 54, 1><<<nbMM, 256, 0, stream>>>(h, nullptr, pool_W + i * HDIM * HDIM,
                                               pool_b + i * HDIM, z, N);
    k_agg<<<(N + 7) / 8, 256, 0, stream>>>(z, csr, rowStart, deg, c, N);
    k_mm<216, 54, 2><<<nbMM, 256, 0, stream>>>(h, c, app_W + i * 2 * HDIM * HDIM,
                                               app_b + i * HDIM, h, N);
  }

  k_cnt_bs<<<1, 128, 0, stream>>>(gid, cnt, N);
  k_readout<<<(N + 8 * 64 - 1) / (8 * 64), 256, 0, stream>>>(h, gid, hg, N);
  k_div<<<(G_GRAPHS * HDIM + 255) / 256, 256, 0, stream>>>(hg, cnt, out, G_GRAPHS * HDIM);
}